// Round 3
// baseline (658.049 us; speedup 1.0000x reference)
//
#include <hip/hip_runtime.h>
#include <hip/hip_bf16.h>

typedef __hip_bfloat16 bf16;

#define B_   32
#define L_   200
#define DIM_ 36
#define ET_  128
#define NH_  64
#define SD_  9
#define NC_  2

// element offsets within d_out (dtype-agnostic)
#define O_TE   0
#define O_T1   147456
#define O_LG   294912
#define O_SXG  294976
#define O_SOUT 336448
#define O_QP   377920

__device__ __forceinline__ float b2f(bf16 v) { return __bfloat162float(v); }
__device__ __forceinline__ bf16  f2b(float v) { return __float2bfloat16(v); }
__device__ __forceinline__ float sigm(float x) { return 1.f / (1.f + expf(-x)); }

// Flag-dispatched load/store: F=1 -> buffers are float32, F=0 -> bfloat16.
__device__ __forceinline__ float ldf(const void* p, size_t i, int F) {
  return F ? ((const float*)p)[i] : b2f(((const bf16*)p)[i]);
}
__device__ __forceinline__ void stf(void* p, size_t i, int F, float v) {
  if (F) ((float*)p)[i] = v;
  else   ((bf16*)p)[i] = f2b(v);
}

// ---------------------------------------------------------------------------
// K-1: dtype detector. Scans first 8192 u16 words of x for bf16 NaN/Inf
// patterns (exp=0xFF). Real bf16 ~N(0,1) data never has them; f32 data read
// as u16 pairs hits them w.p. ~0.78%/elem -> expected ~64 hits.
__global__ __launch_bounds__(256) void k_detect(const void* __restrict__ x,
                                                int* __restrict__ flag) {
  __shared__ int cnt;
  if (threadIdx.x == 0) cnt = 0;
  __syncthreads();
  const unsigned short* p = (const unsigned short*)x;
  int c = 0;
  for (int i = threadIdx.x; i < 8192; i += 256) {
    unsigned short u = p[i];
    if ((u & 0x7F80u) == 0x7F80u) c++;  // bf16 Inf or NaN
  }
  atomicAdd(&cnt, c);
  __syncthreads();
  if (threadIdx.x == 0) flag[0] = (cnt > 0) ? 1 : 0;
}

// ---------------------------------------------------------------------------
// K0: q = time_emb(query_param) @ qw.T + qb  (128x128 f32); qp passthrough.
__global__ __launch_bounds__(128) void k_qmat(
    const void* __restrict__ qp, const void* __restrict__ pw,
    const void* __restrict__ pb, const void* __restrict__ tlw,
    const void* __restrict__ tlb, const void* __restrict__ qw,
    const void* __restrict__ qb, const int* __restrict__ flag,
    float* __restrict__ q_out, void* __restrict__ out) {
  int F = *flag;
  __shared__ float qe[ET_];
  int i = blockIdx.x, j = threadIdx.x;
  float t = ldf(qp, i, F);
  if (j == 0) qe[0] = t * ldf(tlw, 0, F) + ldf(tlb, 0, F);
  else        qe[j] = sinf(t * ldf(pw, j - 1, F) + ldf(pb, j - 1, F));
  __syncthreads();
  float acc = ldf(qb, j, F);
  #pragma unroll 8
  for (int d = 0; d < ET_; d++) acc += qe[d] * ldf(qw, j * ET_ + d, F);
  q_out[i * ET_ + j] = acc;
  if (i == 0) stf(out, O_QP + j, F, ldf(qp, j, F));
}

// ---------------------------------------------------------------------------
// K1: k = time_emb(time_steps) @ kw.T + kb   (B*L x 128, f32)
__global__ __launch_bounds__(128) void k_kmat(
    const void* __restrict__ ts, const void* __restrict__ pw,
    const void* __restrict__ pb, const void* __restrict__ tlw,
    const void* __restrict__ tlb, const void* __restrict__ kw,
    const void* __restrict__ kb, const int* __restrict__ flag,
    float* __restrict__ k_out) {
  int F = *flag;
  __shared__ float ke[ET_];
  int bl = blockIdx.x, j = threadIdx.x;
  float t = ldf(ts, bl, F);
  if (j == 0) ke[0] = t * ldf(tlw, 0, F) + ldf(tlb, 0, F);
  else        ke[j] = sinf(t * ldf(pw, j - 1, F) + ldf(pb, j - 1, F));
  __syncthreads();
  float acc = ldf(kb, j, F);
  #pragma unroll 8
  for (int d = 0; d < ET_; d++) acc += ke[d] * ldf(kw, j * ET_ + d, F);
  k_out[(size_t)bl * ET_ + j] = acc;
}

// ---------------------------------------------------------------------------
// K2: xmean[b][d] = mean_l x[b,l,d]  (uniform-softmax fallback table)
__global__ __launch_bounds__(128) void k_xmean(const void* __restrict__ x,
                                               const int* __restrict__ flag,
                                               float* __restrict__ xmean) {
  int F = *flag;
  int b = blockIdx.x;
  for (int d = threadIdx.x; d < 72; d += 128) {
    float s = 0.f;
    for (int l = 0; l < L_; l++) s += ldf(x, ((size_t)b * L_ + l) * 72 + d, F);
    xmean[b * 72 + d] = s * (1.0f / L_);
  }
}

// ---------------------------------------------------------------------------
// K3 (fused): scores -> rowmax -> e in LDS -> on-the-fly masked num/den sums
// -> divisions (+mean fallback) -> output projection. Writes out_te, out1_te,
// and an f32 copy of out_te for downstream kernels.
__global__ __launch_bounds__(256) void k_attn(
    const float* __restrict__ qm, const float* __restrict__ km,
    const void* __restrict__ x, const int* __restrict__ rm,
    const float* __restrict__ xmean, const void* __restrict__ ow,
    const void* __restrict__ ob, const int* __restrict__ flag,
    void* __restrict__ out, float* __restrict__ otef) {
  int F = *flag;
  __shared__ float qs[16][ET_ + 1];
  __shared__ float ks[16][ET_ + 1];
  __shared__ float sc[16][L_];
  __shared__ float wsh[16][144];
  __shared__ float ofr[16][144];
  __shared__ float owsh[DIM_][72];
  int b = blockIdx.x >> 3;
  int q0 = (blockIdx.x & 7) << 4;
  int tid = threadIdx.x;
  int qi = tid >> 4, li = tid & 15;

  for (int idx = tid; idx < 16 * ET_; idx += 256)
    qs[idx >> 7][idx & 127] = qm[(q0 + (idx >> 7)) * ET_ + (idx & 127)];
  for (int idx = tid; idx < DIM_ * 72; idx += 256)
    owsh[idx / 72][idx % 72] = ldf(ow, idx, F);

  const float* kbp = km + (size_t)b * L_ * ET_;
  for (int l0 = 0; l0 < L_; l0 += 16) {
    int nl = min(16, L_ - l0);
    __syncthreads();
    for (int idx = tid; idx < nl * ET_; idx += 256)
      ks[idx >> 7][idx & 127] =
          kbp[(size_t)(l0 + (idx >> 7)) * ET_ + (idx & 127)];
    __syncthreads();
    if (li < nl) {
      float a = 0.f;
      #pragma unroll 8
      for (int d = 0; d < ET_; d++) a += qs[qi][d] * ks[li][d];
      sc[qi][l0 + li] = a * 0.088388347648318447f;  // 1/sqrt(128)
    }
  }
  __syncthreads();

  {
    float m = -1e30f;
    for (int l = li; l < L_; l += 16) m = fmaxf(m, sc[qi][l]);
    #pragma unroll
    for (int off = 8; off >= 1; off >>= 1) m = fmaxf(m, __shfl_xor(m, off));
    for (int l = li; l < L_; l += 16) sc[qi][l] = expf(sc[qi][l] - m);
  }
  __syncthreads();

  float acc[9];
  #pragma unroll
  for (int r = 0; r < 9; r++) acc[r] = 0.f;
  const size_t xb = (size_t)b * L_ * 72;
  const int* rmb = rm + b * L_;
  for (int l0 = 0; l0 < L_; l0 += 16) {
    int nl = min(16, L_ - l0);
    __syncthreads();
    for (int idx = tid; idx < nl * 144; idx += 256) {
      int l = idx / 144, c = idx % 144;
      int f = c % DIM_, seg = c / DIM_;
      float vv = ldf(x, xb + (size_t)(l0 + l) * 72 + f, F);
      float oo = ldf(x, xb + (size_t)(l0 + l) * 72 + 36 + f, F);
      float rr = (float)rmb[l0 + l];
      float w;
      if (seg == 0)      w = oo * vv;
      else if (seg == 1) w = oo;
      else if (seg == 2) w = oo * vv * rr;
      else               w = oo * rr;
      wsh[l][c] = w;
    }
    __syncthreads();
    for (int l = 0; l < nl; l++) {
      float ev = sc[qi][l0 + l];
      #pragma unroll
      for (int r = 0; r < 9; r++) acc[r] += ev * wsh[l][li + r * 16];
    }
  }
  __syncthreads();
  #pragma unroll
  for (int r = 0; r < 9; r++) wsh[qi][li + r * 16] = acc[r];
  __syncthreads();

  const float* xm = xmean + b * 72;
  for (int idx = tid; idx < 16 * DIM_; idx += 256) {
    int qq = idx / DIM_, j = idx % DIM_;
    float numA = wsh[qq][j],      denA = wsh[qq][36 + j];
    float numB = wsh[qq][72 + j], denB = wsh[qq][108 + j];
    float al, ah, bl, bh;
    if (denA > 0.f) { al = numA / denA; ah = 1.f; }
    else            { al = xm[j];       ah = xm[36 + j]; }
    if (denB > 0.f) { bl = numB / denB; bh = 1.f; }
    else            { bl = xm[j];       bh = xm[36 + j]; }
    ofr[qq][j] = al;      ofr[qq][36 + j] = ah;
    ofr[qq][72 + j] = bl; ofr[qq][108 + j] = bh;
  }
  __syncthreads();

  for (int idx = tid; idx < 16 * 72; idx += 256) {
    int qq = idx / 72, t = idx % 72;
    int v = t / DIM_, i = t % DIM_;
    const float* o = &ofr[qq][v * 72];
    float a = ldf(ob, i, F);
    #pragma unroll 8
    for (int d = 0; d < 72; d++) a += o[d] * owsh[i][d];
    size_t off = ((size_t)b * ET_ + q0 + qq) * DIM_ + i;
    if (v == 0) { stf(out, O_TE + off, F, a); otef[off] = a; }
    else        { stf(out, O_T1 + off, F, a); }
  }
}

// ---------------------------------------------------------------------------
// K4: sx_g[b] = round(sigmoid(sx^T sx))   (36x36 over L)
__global__ __launch_bounds__(256) void k_sxg(const void* __restrict__ x,
                                             const int* __restrict__ flag,
                                             void* __restrict__ out) {
  int F = *flag;
  __shared__ float sxs[L_ * DIM_];
  int b = blockIdx.x;
  for (int idx = threadIdx.x; idx < L_ * DIM_; idx += 256) {
    int l = idx / DIM_, j = idx % DIM_;
    sxs[idx] = ldf(x, ((size_t)b * L_ + l) * 72 + j, F);
  }
  __syncthreads();
  for (int idx = threadIdx.x; idx < DIM_ * DIM_; idx += 256) {
    int d = idx / DIM_, e = idx % DIM_;
    float s = 0.f;
    for (int l = 0; l < L_; l++) s += sxs[l * DIM_ + d] * sxs[l * DIM_ + e];
    stf(out, O_SXG + (size_t)b * DIM_ * DIM_ + idx, F, rintf(sigm(s)));
  }
}

// ---------------------------------------------------------------------------
// K5: sout[b] = sigmoid(out_te^T out_te)   (36x36 over ET)
__global__ __launch_bounds__(256) void k_sout(const float* __restrict__ ote,
                                              const int* __restrict__ flag,
                                              void* __restrict__ out) {
  int F = *flag;
  __shared__ float os[ET_ * DIM_];
  int b = blockIdx.x;
  for (int idx = threadIdx.x; idx < ET_ * DIM_; idx += 256)
    os[idx] = ote[(size_t)b * ET_ * DIM_ + idx];
  __syncthreads();
  for (int idx = threadIdx.x; idx < DIM_ * DIM_; idx += 256) {
    int d = idx / DIM_, e = idx % DIM_;
    float s = 0.f;
    for (int q = 0; q < ET_; q++) s += os[q * DIM_ + d] * os[q * DIM_ + e];
    stf(out, O_SOUT + (size_t)b * DIM_ * DIM_ + idx, F, sigm(s));
  }
}

// ---------------------------------------------------------------------------
// K6: GRU scan, gi computed on the fly (xt prefetched into LDS by threads
// 64..99 while threads 0..63 update h).
__global__ __launch_bounds__(192) void k_gru(const float* __restrict__ ote,
                                             const void* __restrict__ wih,
                                             const void* __restrict__ bih,
                                             const void* __restrict__ whh,
                                             const void* __restrict__ bhh,
                                             const int* __restrict__ flag,
                                             float* __restrict__ hfin) {
  int F = *flag;
  __shared__ __align__(16) float h[NH_];
  __shared__ float xt[DIM_];
  __shared__ float gh[192];
  __shared__ float gis[192];
  int b = blockIdx.x, j = threadIdx.x;
  float w[NH_], wr[DIM_];
  #pragma unroll
  for (int d = 0; d < NH_; d++) w[d] = ldf(whh, j * NH_ + d, F);
  #pragma unroll
  for (int d = 0; d < DIM_; d++) wr[d] = ldf(wih, j * DIM_ + d, F);
  float bh = ldf(bhh, j, F), bi = ldf(bih, j, F);
  if (j < NH_) h[j] = 0.f;
  if (j >= 64 && j < 64 + DIM_)
    xt[j - 64] = ote[(size_t)b * ET_ * DIM_ + (j - 64)];
  __syncthreads();
  for (int q = 0; q < ET_; q++) {
    const float4* h4 = (const float4*)h;
    float a0 = 0.f, a1 = 0.f, a2 = 0.f, a3 = 0.f;
    #pragma unroll
    for (int d4 = 0; d4 < NH_ / 4; d4++) {
      float4 hv = h4[d4];
      a0 += hv.x * w[d4 * 4 + 0];
      a1 += hv.y * w[d4 * 4 + 1];
      a2 += hv.z * w[d4 * 4 + 2];
      a3 += hv.w * w[d4 * 4 + 3];
    }
    float giv = bi;
    #pragma unroll
    for (int d = 0; d < DIM_; d++) giv += xt[d] * wr[d];
    gh[j]  = (a0 + a1) + (a2 + a3) + bh;
    gis[j] = giv;
    __syncthreads();
    if (j < NH_) {
      float r = sigm(gis[j] + gh[j]);
      float z = sigm(gis[NH_ + j] + gh[NH_ + j]);
      float n = tanhf(gis[2 * NH_ + j] + r * gh[2 * NH_ + j]);
      h[j] = (1.f - z) * n + z * h[j];
    } else if (j < 64 + DIM_ && q + 1 < ET_) {
      xt[j - 64] = ote[((size_t)b * ET_ + q + 1) * DIM_ + (j - 64)];
    }
    __syncthreads();
  }
  if (j < NH_) hfin[b * NH_ + j] = h[j];
}

// ---------------------------------------------------------------------------
// K7: classifier head: st, concat, c1, batchnorm(batch), gelu, c2 -> logits
__global__ __launch_bounds__(256) void k_cls(
    const float* __restrict__ hfin, const void* __restrict__ si,
    const void* __restrict__ stw, const void* __restrict__ stb,
    const void* __restrict__ c1w, const void* __restrict__ c1b,
    const void* __restrict__ bng, const void* __restrict__ bnb,
    const void* __restrict__ c2w, const void* __restrict__ c2b,
    const int* __restrict__ flag, void* __restrict__ out) {
  int F = *flag;
  __shared__ float cin[B_][72];
  __shared__ float z1[B_][72];
  __shared__ float zg[B_][72];
  int t = threadIdx.x;
  for (int idx = t; idx < B_ * 8; idx += 256) {
    int b = idx / 8, j = idx % 8;
    float acc = ldf(stb, j, F);
    #pragma unroll
    for (int d = 0; d < SD_; d++)
      acc += ldf(si, b * SD_ + d, F) * ldf(stw, j * SD_ + d, F);
    cin[b][NH_ + j] = acc;
  }
  for (int idx = t; idx < B_ * NH_; idx += 256)
    cin[idx / NH_][idx % NH_] = hfin[idx];
  __syncthreads();
  for (int idx = t; idx < B_ * 72; idx += 256) {
    int b = idx / 72, j = idx % 72;
    float acc = ldf(c1b, j, F);
    #pragma unroll 8
    for (int d = 0; d < 72; d++) acc += cin[b][d] * ldf(c1w, j * 72 + d, F);
    z1[b][j] = acc;
  }
  __syncthreads();
  if (t < 72) {
    float mu = 0.f;
    for (int b = 0; b < B_; b++) mu += z1[b][t];
    mu *= (1.f / B_);
    float vv = 0.f;
    for (int b = 0; b < B_; b++) { float d = z1[b][t] - mu; vv += d * d; }
    vv *= (1.f / B_);
    float inv = 1.f / sqrtf(vv + 1e-5f);
    float g = ldf(bng, t, F), bb = ldf(bnb, t, F);
    for (int b = 0; b < B_; b++) {
      float zn = (z1[b][t] - mu) * inv * g + bb;
      zg[b][t] = 0.5f * zn * (1.f + erff(zn * 0.70710678118654752f));
    }
  }
  __syncthreads();
  for (int idx = t; idx < B_ * NC_; idx += 256) {
    int b = idx / NC_, c = idx % NC_;
    float acc = ldf(c2b, c, F);
    #pragma unroll 8
    for (int d = 0; d < 72; d++) acc += zg[b][d] * ldf(c2w, c * 72 + d, F);
    stf(out, O_LG + idx, F, acc);
  }
}

// ---------------------------------------------------------------------------
extern "C" void kernel_launch(void* const* d_in, const int* in_sizes, int n_in,
                              void* d_out, int out_size, void* d_ws,
                              size_t ws_size, hipStream_t stream) {
  const void* x    = d_in[0];
  const void* ts   = d_in[1];
  const void* si   = d_in[2];
  const void* qp   = d_in[3];
  const void* pw   = d_in[4];
  const void* pb   = d_in[5];
  const void* tlw  = d_in[6];
  const void* tlb  = d_in[7];
  const void* qw   = d_in[8];
  const void* qb   = d_in[9];
  const void* kw   = d_in[10];
  const void* kb   = d_in[11];
  const void* ow   = d_in[12];
  const void* ob   = d_in[13];
  const void* wih  = d_in[14];
  const void* whh  = d_in[15];
  const void* bih  = d_in[16];
  const void* bhh  = d_in[17];
  const void* stw  = d_in[18];
  const void* stb  = d_in[19];
  const void* c1w  = d_in[20];
  const void* c1b  = d_in[21];
  const void* bng  = d_in[22];
  const void* bnb  = d_in[23];
  const void* c2w  = d_in[24];
  const void* c2b  = d_in[25];
  const int*  rm   = (const int*)d_in[26];

  // workspace: 987,408 floats = 3.95 MB
  float* W = (float*)d_ws;
  int*   ws_flag  = (int*)W;             // 16 floats reserved
  float* ws_q     = W + 16;              // 16384
  float* ws_k     = W + 16400;           // 819200
  float* ws_xmean = W + 835600;          // 2304
  float* ws_ote   = W + 837904;          // 147456
  float* ws_hfin  = W + 985360;          // 2048

  hipLaunchKernelGGL(k_detect, dim3(1), dim3(256), 0, stream, x, ws_flag);
  hipLaunchKernelGGL(k_qmat, dim3(ET_), dim3(ET_), 0, stream,
                     qp, pw, pb, tlw, tlb, qw, qb, ws_flag, ws_q, d_out);
  hipLaunchKernelGGL(k_kmat, dim3(B_ * L_), dim3(ET_), 0, stream,
                     ts, pw, pb, tlw, tlb, kw, kb, ws_flag, ws_k);
  hipLaunchKernelGGL(k_xmean, dim3(B_), dim3(128), 0, stream,
                     x, ws_flag, ws_xmean);
  hipLaunchKernelGGL(k_attn, dim3(B_ * 8), dim3(256), 0, stream,
                     ws_q, ws_k, x, rm, ws_xmean, ow, ob, ws_flag,
                     d_out, ws_ote);
  hipLaunchKernelGGL(k_sxg, dim3(B_), dim3(256), 0, stream, x, ws_flag, d_out);
  hipLaunchKernelGGL(k_sout, dim3(B_), dim3(256), 0, stream,
                     ws_ote, ws_flag, d_out);
  hipLaunchKernelGGL(k_gru, dim3(B_), dim3(192), 0, stream,
                     ws_ote, wih, bih, whh, bhh, ws_flag, ws_hfin);
  hipLaunchKernelGGL(k_cls, dim3(1), dim3(256), 0, stream,
                     ws_hfin, si, stw, stb, c1w, c1b, bng, bnb, c2w, c2b,
                     ws_flag, d_out);
}

// Round 4
// 383.688 us; speedup vs baseline: 1.7151x; 1.7151x over previous
//
#include <hip/hip_runtime.h>

#define B_   32
#define L_   200
#define DIM_ 36
#define ET_  128
#define NH_  64
#define SD_  9
#define NC_  2

// element offsets within d_out (float32)
#define O_TE   0
#define O_T1   147456
#define O_LG   294912
#define O_SXG  294976
#define O_SOUT 336448
#define O_QP   377920

__device__ __forceinline__ float sigm(float x) { return 1.f / (1.f + expf(-x)); }

// ---------------------------------------------------------------------------
// K0: raw key time-embeddings e_k[b*l][128] (no kw projection needed; folded
// into qm2 via M = qw^T kw). Coalesced grid-stride.
__global__ __launch_bounds__(256) void k_emb(
    const float* __restrict__ ts, const float* __restrict__ pw,
    const float* __restrict__ pb, const float* __restrict__ tlw,
    const float* __restrict__ tlb, float* __restrict__ ek) {
  float tw = tlw[0], tb = tlb[0];
  for (int idx = blockIdx.x * 256 + threadIdx.x; idx < B_ * L_ * ET_;
       idx += 256 * 256) {
    int row = idx >> 7, j = idx & 127;
    float t = ts[row];
    ek[idx] = (j == 0) ? t * tw + tb : sinf(t * pw[j - 1] + pb[j - 1]);
  }
}

// ---------------------------------------------------------------------------
// K1: M[d][e] = sum_i qw[i][d] * kw[i][e]   (128x128, 16x16 tiles)
__global__ __launch_bounds__(256) void k_M(const float* __restrict__ qw,
                                           const float* __restrict__ kw,
                                           float* __restrict__ M) {
  __shared__ float qs[128][17];
  __shared__ float ks[128][17];
  int d0 = (blockIdx.x & 7) << 4, e0 = (blockIdx.x >> 3) << 4;
  for (int idx = threadIdx.x; idx < 128 * 16; idx += 256) {
    int i = idx >> 4, c = idx & 15;
    qs[i][c] = qw[i * 128 + d0 + c];
    ks[i][c] = kw[i * 128 + e0 + c];
  }
  __syncthreads();
  int dd = threadIdx.x & 15, ee = threadIdx.x >> 4;
  float a = 0.f;
  #pragma unroll 8
  for (int i = 0; i < 128; i++) a += qs[i][dd] * ks[i][ee];
  M[(d0 + dd) * 128 + e0 + ee] = a;
}

// ---------------------------------------------------------------------------
// K2: qm2[q][e] = (e_q[q]·M[:,e] + qb·kw[:,e]) / sqrt(128); qp passthrough.
// (q-side constant terms cancel under softmax and are dropped.)
__global__ __launch_bounds__(128) void k_qm2(
    const float* __restrict__ qp, const float* __restrict__ pw,
    const float* __restrict__ pb, const float* __restrict__ tlw,
    const float* __restrict__ tlb, const float* __restrict__ qb,
    const float* __restrict__ kw, const float* __restrict__ M,
    float* __restrict__ qm2, float* __restrict__ out) {
  __shared__ float eq[ET_];
  int q = blockIdx.x, e = threadIdx.x;
  float t = qp[q];
  eq[e] = (e == 0) ? t * tlw[0] + tlb[0] : sinf(t * pw[e - 1] + pb[e - 1]);
  __syncthreads();
  float a = 0.f;
  #pragma unroll 8
  for (int i = 0; i < ET_; i++) a += qb[i] * kw[i * ET_ + e];
  #pragma unroll 8
  for (int d = 0; d < ET_; d++) a += eq[d] * M[d * ET_ + e];
  qm2[q * ET_ + e] = a * 0.088388347648318447f;
  if (q == 0) out[O_QP + e] = qp[e];
}

// ---------------------------------------------------------------------------
// K3: xmean[b][d] = mean_l x[b,l,d] (fallback table). Coalesced over d.
__global__ __launch_bounds__(128) void k_xmean(const float* __restrict__ x,
                                               float* __restrict__ xmean) {
  int b = blockIdx.x;
  int d = threadIdx.x;
  if (d < 72) {
    float s = 0.f;
    #pragma unroll 8
    for (int l = 0; l < L_; l++) s += x[((size_t)b * L_ + l) * 72 + d];
    xmean[b * 72 + d] = s * (1.0f / L_);
  }
}

// ---------------------------------------------------------------------------
// K4 (fused attention): scores (qm2·e_k) -> rowmax -> e in LDS -> on-the-fly
// masked num/den sums -> divisions (+mean fallback) -> output projection.
// Writes out_te, out1_te (f32, directly to d_out).
__global__ __launch_bounds__(256) void k_attn(
    const float* __restrict__ qm, const float* __restrict__ ek,
    const float* __restrict__ x, const int* __restrict__ rm,
    const float* __restrict__ xmean, const float* __restrict__ ow,
    const float* __restrict__ ob, float* __restrict__ out) {
  __shared__ __align__(16) float qs[16][132];
  __shared__ __align__(16) float ks[16][132];
  __shared__ float sc[16][L_];
  __shared__ __align__(16) float xs[16][72];
  __shared__ float wsh[16][144];
  __shared__ float ofr[16][144];
  __shared__ __align__(16) float owsh[DIM_][72];
  __shared__ float rms[16];
  int b = blockIdx.x >> 3;
  int q0 = (blockIdx.x & 7) << 4;
  int tid = threadIdx.x;
  int qi = tid >> 4, li = tid & 15;

  // stage q-tile (float4) and ow
  const float4* qsrc = (const float4*)(qm + q0 * ET_);
  for (int idx = tid; idx < 16 * 32; idx += 256)
    ((float4*)qs[idx >> 5])[idx & 31] = qsrc[idx];
  const float4* owsrc = (const float4*)ow;
  for (int idx = tid; idx < DIM_ * 18; idx += 256)
    ((float4*)owsh[idx / 18])[idx % 18] = owsrc[idx];

  // --- scores: sc[q][l] = qm2[q]·ek[b,l] ---
  const float* kbp = ek + (size_t)b * L_ * ET_;
  for (int l0 = 0; l0 < L_; l0 += 16) {
    int nl = min(16, L_ - l0);
    __syncthreads();
    const float4* ksrc = (const float4*)(kbp + (size_t)l0 * ET_);
    for (int idx = tid; idx < nl * 32; idx += 256)
      ((float4*)ks[idx >> 5])[idx & 31] = ksrc[idx];
    __syncthreads();
    if (li < nl) {
      const float4* q4 = (const float4*)qs[qi];
      const float4* k4 = (const float4*)ks[li];
      float a0 = 0.f, a1 = 0.f, a2 = 0.f, a3 = 0.f;
      #pragma unroll 8
      for (int d4 = 0; d4 < 32; d4++) {
        float4 qv = q4[d4], kv = k4[d4];
        a0 += qv.x * kv.x; a1 += qv.y * kv.y;
        a2 += qv.z * kv.z; a3 += qv.w * kv.w;
      }
      sc[qi][l0 + li] = (a0 + a1) + (a2 + a3);
    }
  }
  __syncthreads();

  // --- rowmax + exp in place ---
  {
    float m = -1e30f;
    for (int l = li; l < L_; l += 16) m = fmaxf(m, sc[qi][l]);
    #pragma unroll
    for (int off = 8; off >= 1; off >>= 1) m = fmaxf(m, __shfl_xor(m, off));
    for (int l = li; l < L_; l += 16) sc[qi][l] = expf(sc[qi][l] - m);
  }
  __syncthreads();

  // --- masked weighted sums: (16q x 200) e @ (200 x 144) on-the-fly weights
  float acc[9];
  #pragma unroll
  for (int r = 0; r < 9; r++) acc[r] = 0.f;
  const float* xb = x + (size_t)b * L_ * 72;
  const int* rmb = rm + b * L_;
  for (int l0 = 0; l0 < L_; l0 += 16) {
    int nl = min(16, L_ - l0);
    __syncthreads();
    const float4* xsrc = (const float4*)(xb + (size_t)l0 * 72);
    for (int idx = tid; idx < nl * 18; idx += 256)
      ((float4*)xs[idx / 18])[idx % 18] = xsrc[idx];
    if (tid < nl) rms[tid] = (float)rmb[l0 + tid];
    __syncthreads();
    for (int idx = tid; idx < nl * 144; idx += 256) {
      int l = idx / 144, c = idx % 144;
      int f = c % DIM_, seg = c / DIM_;
      float vv = xs[l][f], oo = xs[l][36 + f], rr = rms[l];
      float w;
      if (seg == 0)      w = oo * vv;
      else if (seg == 1) w = oo;
      else if (seg == 2) w = oo * vv * rr;
      else               w = oo * rr;
      wsh[l][c] = w;
    }
    __syncthreads();
    for (int l = 0; l < nl; l++) {
      float ev = sc[qi][l0 + l];
      #pragma unroll
      for (int r = 0; r < 9; r++) acc[r] += ev * wsh[l][li + r * 16];
    }
  }
  __syncthreads();
  #pragma unroll
  for (int r = 0; r < 9; r++) wsh[qi][li + r * 16] = acc[r];
  __syncthreads();

  // --- divisions + uniform-mean fallback ---
  const float* xm = xmean + b * 72;
  for (int idx = tid; idx < 16 * DIM_; idx += 256) {
    int qq = idx / DIM_, j = idx % DIM_;
    float numA = wsh[qq][j],      denA = wsh[qq][36 + j];
    float numB = wsh[qq][72 + j], denB = wsh[qq][108 + j];
    float al, ah, bl, bh;
    if (denA > 0.f) { al = numA / denA; ah = 1.f; }
    else            { al = xm[j];       ah = xm[36 + j]; }
    if (denB > 0.f) { bl = numB / denB; bh = 1.f; }
    else            { bl = xm[j];       bh = xm[36 + j]; }
    ofr[qq][j] = al;      ofr[qq][36 + j] = ah;
    ofr[qq][72 + j] = bl; ofr[qq][108 + j] = bh;
  }
  __syncthreads();

  // --- output projection ---
  for (int idx = tid; idx < 16 * 72; idx += 256) {
    int qq = idx / 72, t = idx % 72;
    int v = t / DIM_, i = t % DIM_;
    const float* o = &ofr[qq][v * 72];
    float a = ob[i];
    #pragma unroll 8
    for (int d = 0; d < 72; d++) a += o[d] * owsh[i][d];
    size_t off = ((size_t)b * ET_ + q0 + qq) * DIM_ + i;
    out[(v == 0 ? O_TE : O_T1) + off] = a;
  }
}

// ---------------------------------------------------------------------------
// K5: sx_g[b] = round(sigmoid(sx^T sx))   (36x36 over L)
__global__ __launch_bounds__(256) void k_sxg(const float* __restrict__ x,
                                             float* __restrict__ out) {
  __shared__ __align__(16) float sxs[L_][DIM_];
  int b = blockIdx.x;
  const float4* xsrc = (const float4*)(x + (size_t)b * L_ * 72);
  for (int idx = threadIdx.x; idx < L_ * 9; idx += 256) {
    int l = idx / 9, c = idx % 9;
    ((float4*)sxs[l])[c] = xsrc[l * 18 + c];
  }
  __syncthreads();
  for (int idx = threadIdx.x; idx < DIM_ * DIM_; idx += 256) {
    int d = idx / DIM_, e = idx % DIM_;
    float s = 0.f;
    #pragma unroll 8
    for (int l = 0; l < L_; l++) s += sxs[l][d] * sxs[l][e];
    out[O_SXG + (size_t)b * DIM_ * DIM_ + idx] = rintf(sigm(s));
  }
}

// ---------------------------------------------------------------------------
// K6: sout[b] = sigmoid(out_te^T out_te)   (36x36 over ET), reads f32 d_out
__global__ __launch_bounds__(256) void k_sout(const float* __restrict__ out_ro,
                                              float* __restrict__ out) {
  __shared__ __align__(16) float os[ET_][DIM_];
  int b = blockIdx.x;
  const float4* osrc = (const float4*)(out_ro + O_TE + (size_t)b * ET_ * DIM_);
  for (int idx = threadIdx.x; idx < ET_ * 9; idx += 256)
    ((float4*)os[idx / 9])[idx % 9] = osrc[idx];
  __syncthreads();
  for (int idx = threadIdx.x; idx < DIM_ * DIM_; idx += 256) {
    int d = idx / DIM_, e = idx % DIM_;
    float s = 0.f;
    #pragma unroll 8
    for (int q = 0; q < ET_; q++) s += os[q][d] * os[q][e];
    out[O_SOUT + (size_t)b * DIM_ * DIM_ + idx] = sigm(s);
  }
}

// ---------------------------------------------------------------------------
// K7: GRU scan; gi computed on the fly (xt prefetch by threads 64..99).
__global__ __launch_bounds__(192) void k_gru(const float* __restrict__ out_ro,
                                             const float* __restrict__ wih,
                                             const float* __restrict__ bih,
                                             const float* __restrict__ whh,
                                             const float* __restrict__ bhh,
                                             float* __restrict__ hfin) {
  __shared__ __align__(16) float h[NH_];
  __shared__ float xt[DIM_];
  __shared__ float gh[192];
  __shared__ float gis[192];
  const float* ote = out_ro + O_TE;
  int b = blockIdx.x, j = threadIdx.x;
  float w[NH_], wr[DIM_];
  #pragma unroll
  for (int d = 0; d < NH_; d++) w[d] = whh[j * NH_ + d];
  #pragma unroll
  for (int d = 0; d < DIM_; d++) wr[d] = wih[j * DIM_ + d];
  float bh = bhh[j], bi = bih[j];
  if (j < NH_) h[j] = 0.f;
  if (j >= 64 && j < 64 + DIM_)
    xt[j - 64] = ote[(size_t)b * ET_ * DIM_ + (j - 64)];
  __syncthreads();
  for (int q = 0; q < ET_; q++) {
    const float4* h4 = (const float4*)h;
    float a0 = 0.f, a1 = 0.f, a2 = 0.f, a3 = 0.f;
    #pragma unroll
    for (int d4 = 0; d4 < NH_ / 4; d4++) {
      float4 hv = h4[d4];
      a0 += hv.x * w[d4 * 4 + 0];
      a1 += hv.y * w[d4 * 4 + 1];
      a2 += hv.z * w[d4 * 4 + 2];
      a3 += hv.w * w[d4 * 4 + 3];
    }
    float giv = bi;
    #pragma unroll
    for (int d = 0; d < DIM_; d++) giv += xt[d] * wr[d];
    gh[j]  = (a0 + a1) + (a2 + a3) + bh;
    gis[j] = giv;
    __syncthreads();
    if (j < NH_) {
      float r = sigm(gis[j] + gh[j]);
      float z = sigm(gis[NH_ + j] + gh[NH_ + j]);
      float n = tanhf(gis[2 * NH_ + j] + r * gh[2 * NH_ + j]);
      h[j] = (1.f - z) * n + z * h[j];
    } else if (j < 64 + DIM_ && q + 1 < ET_) {
      xt[j - 64] = ote[((size_t)b * ET_ + q + 1) * DIM_ + (j - 64)];
    }
    __syncthreads();
  }
  if (j < NH_) hfin[b * NH_ + j] = h[j];
}

// ---------------------------------------------------------------------------
// K8: classifier head: st, concat, c1, batchnorm(batch), gelu, c2 -> logits
__global__ __launch_bounds__(256) void k_cls(
    const float* __restrict__ hfin, const float* __restrict__ si,
    const float* __restrict__ stw, const float* __restrict__ stb,
    const float* __restrict__ c1w, const float* __restrict__ c1b,
    const float* __restrict__ bng, const float* __restrict__ bnb,
    const float* __restrict__ c2w, const float* __restrict__ c2b,
    float* __restrict__ out) {
  __shared__ float cin[B_][72];
  __shared__ float z1[B_][72];
  __shared__ float zg[B_][72];
  int t = threadIdx.x;
  for (int idx = t; idx < B_ * 8; idx += 256) {
    int b = idx / 8, j = idx % 8;
    float acc = stb[j];
    #pragma unroll
    for (int d = 0; d < SD_; d++) acc += si[b * SD_ + d] * stw[j * SD_ + d];
    cin[b][NH_ + j] = acc;
  }
  for (int idx = t; idx < B_ * NH_; idx += 256)
    cin[idx / NH_][idx % NH_] = hfin[idx];
  __syncthreads();
  for (int idx = t; idx < B_ * 72; idx += 256) {
    int b = idx / 72, j = idx % 72;
    float acc = c1b[j];
    #pragma unroll 8
    for (int d = 0; d < 72; d++) acc += cin[b][d] * c1w[j * 72 + d];
    z1[b][j] = acc;
  }
  __syncthreads();
  if (t < 72) {
    float mu = 0.f;
    for (int b = 0; b < B_; b++) mu += z1[b][t];
    mu *= (1.f / B_);
    float vv = 0.f;
    for (int b = 0; b < B_; b++) { float d = z1[b][t] - mu; vv += d * d; }
    vv *= (1.f / B_);
    float inv = 1.f / sqrtf(vv + 1e-5f);
    float g = bng[t], bb = bnb[t];
    for (int b = 0; b < B_; b++) {
      float zn = (z1[b][t] - mu) * inv * g + bb;
      zg[b][t] = 0.5f * zn * (1.f + erff(zn * 0.70710678118654752f));
    }
  }
  __syncthreads();
  for (int idx = t; idx < B_ * NC_; idx += 256) {
    int b = idx / NC_, c = idx % NC_;
    float acc = c2b[c];
    #pragma unroll 8
    for (int d = 0; d < 72; d++) acc += zg[b][d] * c2w[c * 72 + d];
    out[O_LG + idx] = acc;
  }
}

// ---------------------------------------------------------------------------
extern "C" void kernel_launch(void* const* d_in, const int* in_sizes, int n_in,
                              void* d_out, int out_size, void* d_ws,
                              size_t ws_size, hipStream_t stream) {
  const float* x    = (const float*)d_in[0];
  const float* ts   = (const float*)d_in[1];
  const float* si   = (const float*)d_in[2];
  const float* qp   = (const float*)d_in[3];
  const float* pw   = (const float*)d_in[4];
  const float* pb   = (const float*)d_in[5];
  const float* tlw  = (const float*)d_in[6];
  const float* tlb  = (const float*)d_in[7];
  const float* qw   = (const float*)d_in[8];
  const float* qb   = (const float*)d_in[9];
  const float* kw   = (const float*)d_in[10];
  const float* ow   = (const float*)d_in[12];
  const float* ob   = (const float*)d_in[13];
  const float* wih  = (const float*)d_in[14];
  const float* whh  = (const float*)d_in[15];
  const float* bih  = (const float*)d_in[16];
  const float* bhh  = (const float*)d_in[17];
  const float* stw  = (const float*)d_in[18];
  const float* stb  = (const float*)d_in[19];
  const float* c1w  = (const float*)d_in[20];
  const float* c1b  = (const float*)d_in[21];
  const float* bng  = (const float*)d_in[22];
  const float* bnb  = (const float*)d_in[23];
  const float* c2w  = (const float*)d_in[24];
  const float* c2b  = (const float*)d_in[25];
  const int*   rm   = (const int*)d_in[26];

  float* out = (float*)d_out;

  // workspace: 856,320 floats = 3.43 MB
  float* W = (float*)d_ws;
  float* ws_ek    = W;            // 819200
  float* ws_qm2   = W + 819200;   // 16384
  float* ws_M     = W + 835584;   // 16384
  float* ws_xmean = W + 851968;   // 2304
  float* ws_hfin  = W + 854272;   // 2048

  hipLaunchKernelGGL(k_emb, dim3(256), dim3(256), 0, stream,
                     ts, pw, pb, tlw, tlb, ws_ek);
  hipLaunchKernelGGL(k_M, dim3(64), dim3(256), 0, stream, qw, kw, ws_M);
  hipLaunchKernelGGL(k_qm2, dim3(ET_), dim3(ET_), 0, stream,
                     qp, pw, pb, tlw, tlb, qb, kw, ws_M, ws_qm2, out);
  hipLaunchKernelGGL(k_xmean, dim3(B_), dim3(128), 0, stream, x, ws_xmean);
  hipLaunchKernelGGL(k_attn, dim3(B_ * 8), dim3(256), 0, stream,
                     ws_qm2, ws_ek, x, rm, ws_xmean, ow, ob, out);
  hipLaunchKernelGGL(k_sxg, dim3(B_), dim3(256), 0, stream, x, out);
  hipLaunchKernelGGL(k_sout, dim3(B_), dim3(256), 0, stream, out, out);
  hipLaunchKernelGGL(k_gru, dim3(B_), dim3(192), 0, stream,
                     out, wih, bih, whh, bhh, ws_hfin);
  hipLaunchKernelGGL(k_cls, dim3(1), dim3(256), 0, stream,
                     ws_hfin, si, stw, stb, c1w, c1b, bng, bnb, c2w, c2b,
                     out);
}